// Round 14
// baseline (257.813 us; speedup 1.0000x reference)
//
#include <hip/hip_runtime.h>
#include <cstddef>

#define NTOK 1024
#define DMODEL 512
#define NHEAD 8
#define DKH 64
#define NSPLIT 4
#define JQ 256

typedef __attribute__((ext_vector_type(4))) float f32x4;
typedef __attribute__((ext_vector_type(8))) __bf16 bf16x8;
typedef __attribute__((ext_vector_type(4))) __bf16 bf16x4;
typedef __attribute__((ext_vector_type(4))) unsigned short u16x4;
typedef __attribute__((ext_vector_type(8))) unsigned short u16x8;
typedef __attribute__((ext_vector_type(4))) _Float16 f16x4;
typedef unsigned short ushort_t;

__device__ __forceinline__ float wave_sum_f(float v){
  #pragma unroll
  for (int m=1; m<64; m<<=1) v += __shfl_xor(v, m, 64);
  return v;
}
__device__ __forceinline__ unsigned short f2bf(float f){
  __bf16 b = (__bf16)f;
  return __builtin_bit_cast(unsigned short, b);
}
__device__ __forceinline__ float bf2f(unsigned short u){
  return (float)__builtin_bit_cast(__bf16, u);
}

// ---- native transcendental ops ----
__device__ __forceinline__ float fract_hw(float x){
  float r; asm("v_fract_f32 %0, %1" : "=v"(r) : "v"(x)); return r;
}
__device__ __forceinline__ float sin_rev(float rev){
  float f = fract_hw(rev);
  float s; asm("v_sin_f32 %0, %1" : "=v"(s) : "v"(f)); return s;
}
__device__ __forceinline__ float cos_rev(float rev){
  float f = fract_hw(rev);
  float c; asm("v_cos_f32 %0, %1" : "=v"(c) : "v"(f)); return c;
}
__device__ __forceinline__ float log_hw(float x){
  float l; asm("v_log_f32 %0, %1" : "=v"(l) : "v"(x));
  return 0.69314718056f * l;
}
__device__ __forceinline__ float exp_hw(float x){
  float y = x * 1.44269504f;
  float e; asm("v_exp_f32 %0, %1" : "=v"(e) : "v"(y));
  return e;
}

// producer completion: all-threads-synced, then lane0 release-add
__device__ __forceinline__ void mark_done(unsigned* c){
  __syncthreads();
  if (threadIdx.x == 0)
    __hip_atomic_fetch_add(c, 1u, __ATOMIC_RELEASE, __HIP_MEMORY_SCOPE_AGENT);
}
// consumer gate: lane0 spin-acquires, then block barrier
__device__ __forceinline__ void wait_for(unsigned* c, unsigned target){
  if (threadIdx.x == 0){
    while (__hip_atomic_load(c, __ATOMIC_ACQUIRE, __HIP_MEMORY_SCOPE_AGENT) < target)
      __builtin_amdgcn_s_sleep(8);
  }
  __syncthreads();
}

// ================= single-launch pipeline, flag-gated =================
// blocks [0,1024)   : gate (1 i each, 8 waves x 128-j)            -> c0++
// blocks [1024,1216): QKV 64x64 tiles, 2 tiles/block, LDS-cvt     -> c0++
// blocks [1216,1280): Wo fp32->bf16 cvt                           -> c0++
// blocks [1280,1536): attn (waits c0==1280)                       -> c1++
// blocks [1536,1664): back: combine+LN0+O-proj+LN (waits c1==256)
__global__ __launch_bounds__(512) void k_all(
    const float* __restrict__ box, const float* __restrict__ WGw, const float* __restrict__ WGb,
    _Float16* __restrict__ wg16,
    const float* __restrict__ inq, const float* __restrict__ ink, const float* __restrict__ inv,
    const float* __restrict__ Wq, const float* __restrict__ Wk, const float* __restrict__ Wv,
    const float* __restrict__ Wo,
    const float* __restrict__ bq, const float* __restrict__ bk, const float* __restrict__ bv,
    ushort_t* __restrict__ Qb, ushort_t* __restrict__ Kb, ushort_t* __restrict__ Vt,
    ushort_t* __restrict__ Wob,
    ushort_t* __restrict__ Xpt, float* __restrict__ rsp,
    const float* __restrict__ ln0g, const float* __restrict__ ln0b,
    const float* __restrict__ bo, const float* __restrict__ lng, const float* __restrict__ lnb,
    float* __restrict__ out, unsigned* bar){
  __shared__ __align__(16) char smem[68608];
  const int t = threadIdx.x;
  const int b = blockIdx.x;
  const int lane = t & 63, w = t >> 6, li = lane & 15, g = lane >> 4;

  if (b < 1024){
    // ================= gate: one i, 8 waves x 128-j =================
    float* arr = (float*)smem;   // [4][1024] = 16 KB
    #pragma unroll
    for (int u2=0; u2<2; u2++){
      int idx = u2*512 + t;
      float4 b4 = *(const float4*)(box + idx*4);
      arr[idx]        = (b4.x + b4.z)*0.5f;
      arr[1024+idx]   = (b4.y + b4.w)*0.5f;
      arr[2048+idx]   = log_hw(b4.z - b4.x + 1.0f);
      arr[3072+idx]   = log_hw(b4.w - b4.y + 1.0f);
    }
    const int i = b;
    float4 bi = *(const float4*)(box + i*4);
    float wi = bi.z - bi.x + 1.0f, hi = bi.w - bi.y + 1.0f;
    float Pi = (g==0) ? (bi.x+bi.z)*0.5f : (g==1) ? (bi.y+bi.w)*0.5f
             : (g==2) ? log_hw(wi) : log_hw(hi);
    float Ri = (g==0) ? 1.0f/wi : (g==1) ? 1.0f/hi : 1.0f;
    const bool doLog = (g < 2);
    bf16x8 wfs = {}, wfc = {};
    float wgb_li = 0.0f;
    if (li < 8){
      #pragma unroll
      for (int e=0; e<8; e++){
        wfs[e] = (__bf16)WGw[li*64 + g*8 + e];
        wfc[e] = (__bf16)WGw[li*64 + 32 + g*8 + e];
      }
      wgb_li = WGb[li];
    }
    __syncthreads();
    const float* parr = arr + g*1024;
    const float DMrev[8] = {15.9154943f, 6.7115094f, 2.8302196f, 1.1934938f,
                            0.5032921f, 0.2122365f, 0.08949941f, 0.0377416f};
    const int jbeg = w*128;
    for (int it=0; it<8; ++it){
      int j = jbeg + it*16 + li;
      float diff = (Pi - parr[j])*Ri;
      float lg = log_hw(fmaxf(fabsf(diff), 1e-3f));
      float dv = doLog ? lg : diff;
      bf16x8 afs, afc;
      #pragma unroll
      for (int e=0; e<8; e++){
        float rev = dv * DMrev[e];
        afs[e] = (__bf16)sin_rev(rev);
        afc[e] = (__bf16)cos_rev(rev);
      }
      f32x4 acc = (f32x4){0.f,0.f,0.f,0.f};
      acc = __builtin_amdgcn_mfma_f32_16x16x32_bf16(afs, wfs, acc, 0,0,0);
      acc = __builtin_amdgcn_mfma_f32_16x16x32_bf16(afc, wfc, acc, 0,0,0);
      if (li < 8){
        f16x4 o;
        #pragma unroll
        for (int r=0; r<4; r++)
          o[r] = (_Float16)fmaxf(acc[r] + wgb_li, 6.103515625e-05f);
        *(f16x4*)(wg16 + (((size_t)li<<20) + ((size_t)i<<10) + jbeg + it*16 + g*4)) = o;
      }
    }
    mark_done(bar);
    return;
  }
  if (b < 1216){
    // ================= QKV: 2 independent 64x64 tiles per block =================
    const int unit = (b - 1024)*2 + (w >> 2);
    const int z = unit >> 7;
    const int rem = unit & 127;
    const int m0 = (rem >> 3)*64;
    const int n0 = (rem & 7)*64;
    const float* A = z==0 ? inq : z==1 ? ink : inv;
    const float* W = z==0 ? Wq : z==1 ? Wk : Wv;
    const float* bias = z==0 ? bq : z==1 ? bk : bv;
    ushort_t* Al = (ushort_t*)(smem + (w>>2)*17408);           // [64][68]
    ushort_t* Wl = (ushort_t*)(smem + (w>>2)*17408 + 8704);    // [64][68]
    const int t2 = t & 255;
    const int row = t2 >> 2, kq = (t2 & 3)*16;
    const int w2 = w & 3;
    const int mrb = (w2 >> 1)*32;
    const int nrb = (w2 & 1)*32;
    f32x4 acc[2][2] = {};
    for (int k0 = 0; k0 < DMODEL; k0 += 64){
      {
        const float* ap = A + (size_t)(m0+row)*DMODEL + k0 + kq;
        const float* wp = W + (size_t)(n0+row)*DMODEL + k0 + kq;
        #pragma unroll
        for (int q=0; q<4; q++){
          float4 av = *(const float4*)(ap + q*4);
          float4 wv = *(const float4*)(wp + q*4);
          u16x4 pa, pw;
          pa[0]=f2bf(av.x); pa[1]=f2bf(av.y); pa[2]=f2bf(av.z); pa[3]=f2bf(av.w);
          pw[0]=f2bf(wv.x); pw[1]=f2bf(wv.y); pw[2]=f2bf(wv.z); pw[3]=f2bf(wv.w);
          *(u16x4*)(Al + row*68 + kq + q*4) = pa;
          *(u16x4*)(Wl + row*68 + kq + q*4) = pw;
        }
      }
      __syncthreads();
      #pragma unroll
      for (int kc=0; kc<64; kc+=32){
        const ushort_t* arl = Al + (mrb + li)*68 + kc + g*8;
        const ushort_t* wrl = Wl + (nrb + li)*68 + kc + g*8;
        bf16x8 af0 = *(const bf16x8*)(arl);
        bf16x8 af1 = *(const bf16x8*)(arl + 16*68);
        bf16x8 wf0 = *(const bf16x8*)(wrl);
        bf16x8 wf1 = *(const bf16x8*)(wrl + 16*68);
        if (z < 2){
          acc[0][0] = __builtin_amdgcn_mfma_f32_16x16x32_bf16(wf0, af0, acc[0][0], 0,0,0);
          acc[0][1] = __builtin_amdgcn_mfma_f32_16x16x32_bf16(wf0, af1, acc[0][1], 0,0,0);
          acc[1][0] = __builtin_amdgcn_mfma_f32_16x16x32_bf16(wf1, af0, acc[1][0], 0,0,0);
          acc[1][1] = __builtin_amdgcn_mfma_f32_16x16x32_bf16(wf1, af1, acc[1][1], 0,0,0);
        } else {
          acc[0][0] = __builtin_amdgcn_mfma_f32_16x16x32_bf16(af0, wf0, acc[0][0], 0,0,0);
          acc[0][1] = __builtin_amdgcn_mfma_f32_16x16x32_bf16(af0, wf1, acc[0][1], 0,0,0);
          acc[1][0] = __builtin_amdgcn_mfma_f32_16x16x32_bf16(af1, wf0, acc[1][0], 0,0,0);
          acc[1][1] = __builtin_amdgcn_mfma_f32_16x16x32_bf16(af1, wf1, acc[1][1], 0,0,0);
        }
      }
      __syncthreads();
    }
    if (z < 2){
      ushort_t* C = z ? Kb : Qb;
      #pragma unroll
      for (int nf=0; nf<2; nf++){
        int n = n0 + nrb + nf*16 + g*4;
        float4 b4 = *(const float4*)(bias + n);
        const float* bp = (const float*)&b4;
        #pragma unroll
        for (int mf=0; mf<2; mf++){
          int m = m0 + mrb + mf*16 + li;
          u16x4 o;
          #pragma unroll
          for (int r=0; r<4; r++) o[r] = f2bf(acc[nf][mf][r] + bp[r]);
          *(u16x4*)(C + (size_t)m*DMODEL + n) = o;
        }
      }
    } else {
      #pragma unroll
      for (int mf=0; mf<2; mf++){
        int m = m0 + mrb + mf*16 + g*4;
        #pragma unroll
        for (int nf=0; nf<2; nf++){
          int n = n0 + nrb + nf*16 + li;
          float bn = bias[n];
          u16x4 o;
          #pragma unroll
          for (int r=0; r<4; r++) o[r] = f2bf(acc[mf][nf][r] + bn);
          *(u16x4*)(Vt + (((size_t)(n>>6))<<16) + ((size_t)(n&63)<<10) + m) = o;
        }
      }
    }
    mark_done(bar);
    return;
  }
  if (b < 1280){
    // ================= Wo fp32 -> bf16 cvt =================
    int off = ((b - 1216)*512 + t)*8;
    float4 a = *(const float4*)(Wo + off);
    float4 b4 = *(const float4*)(Wo + off + 4);
    u16x4 o0, o1;
    o0[0]=f2bf(a.x); o0[1]=f2bf(a.y); o0[2]=f2bf(a.z); o0[3]=f2bf(a.w);
    o1[0]=f2bf(b4.x); o1[1]=f2bf(b4.y); o1[2]=f2bf(b4.z); o1[3]=f2bf(b4.w);
    *(u16x4*)(Wob + off) = o0;
    *(u16x4*)(Wob + off + 4) = o1;
    mark_done(bar);
    return;
  }
  if (b < 1536){
    // ================= attn (R13 k_attn3 verbatim), gated on c0 =================
    wait_for(bar, 1280u);
    ushort_t* Ks = (ushort_t*)smem;            // [256][68] = 34816 B
    ushort_t* Vs = (ushort_t*)(smem + 34816);  // [64][264] = 33792 B
    const int bb = b - 1280;
    const int itg = bb & 7, h = (bb >> 3) & 7, sp = bb >> 6;
    const int jbeg = sp*JQ;
    {
      const int r = t >> 3, c = (t & 7)*8;
      #pragma unroll
      for (int p=0; p<4; p++){
        u16x8 kv = *(const u16x8*)(Kb + (size_t)(jbeg + p*64 + r)*DMODEL + h*DKH + c);
        *(u16x8*)(Ks + (p*64 + r)*68 + c) = kv;
        u16x8 vv = *(const u16x8*)(Vt + ((size_t)h<<16) + (size_t)r*NTOK + jbeg + p*64 + c);
        *(u16x8*)(Vs + r*264 + p*64 + c) = vv;
      }
    }
    const int i0 = (itg*8 + w)*16;
    const ushort_t* qp = Qb + (size_t)(i0+li)*DMODEL + h*DKH + g*8;
    bf16x8 qf0 = *(const bf16x8*)(qp);
    bf16x8 qf1 = *(const bf16x8*)(qp + 32);
    const _Float16* gbase = wg16 + ((size_t)h<<20) + ((size_t)(i0+li)<<10) + jbeg + g*4;
    f32x4 xacc[4];
    #pragma unroll
    for (int mf=0; mf<4; mf++) xacc[mf] = (f32x4){0.f,0.f,0.f,0.f};
    float rsum = 0.f;
    __syncthreads();
    #pragma unroll
    for (int jj = 0; jj < JQ; jj += 32){
      const ushort_t* kp = Ks + (jj + li)*68 + g*8;
      bf16x8 a00 = *(const bf16x8*)(kp);
      bf16x8 a01 = *(const bf16x8*)(kp + 32);
      bf16x8 a10 = *(const bf16x8*)(kp + 16*68);
      bf16x8 a11 = *(const bf16x8*)(kp + 16*68 + 32);
      f32x4 s0 = (f32x4){0.f,0.f,0.f,0.f};
      f32x4 s1 = (f32x4){0.f,0.f,0.f,0.f};
      s0 = __builtin_amdgcn_mfma_f32_16x16x32_bf16(a00, qf0, s0, 0,0,0);
      s0 = __builtin_amdgcn_mfma_f32_16x16x32_bf16(a01, qf1, s0, 0,0,0);
      s1 = __builtin_amdgcn_mfma_f32_16x16x32_bf16(a10, qf0, s1, 0,0,0);
      s1 = __builtin_amdgcn_mfma_f32_16x16x32_bf16(a11, qf1, s1, 0,0,0);
      f16x4 g0 = *(const f16x4*)(gbase + jj);
      f16x4 g1 = *(const f16x4*)(gbase + jj + 16);
      float p[8];
      #pragma unroll
      for (int r=0; r<4; r++){ p[r]   = (float)g0[r] * exp_hw(s0[r]*0.125f); rsum += p[r]; }
      #pragma unroll
      for (int r=0; r<4; r++){ p[4+r] = (float)g1[r] * exp_hw(s1[r]*0.125f); rsum += p[4+r]; }
      bf16x8 pb;
      pb[0]=(__bf16)p[0]; pb[1]=(__bf16)p[1]; pb[2]=(__bf16)p[2]; pb[3]=(__bf16)p[3];
      pb[4]=(__bf16)p[4]; pb[5]=(__bf16)p[5]; pb[6]=(__bf16)p[6]; pb[7]=(__bf16)p[7];
      #pragma unroll
      for (int mf=0; mf<4; mf++){
        const ushort_t* vp = Vs + (size_t)(li + mf*16)*264 + jj + g*4;
        bf16x4 lo = *(const bf16x4*)(vp);
        bf16x4 hi = *(const bf16x4*)(vp + 16);
        bf16x8 vf = __builtin_shufflevector(lo, hi, 0,1,2,3,4,5,6,7);
        xacc[mf] = __builtin_amdgcn_mfma_f32_16x16x32_bf16(vf, pb, xacc[mf], 0,0,0);
      }
    }
    rsum += __shfl_xor(rsum, 16, 64);
    rsum += __shfl_xor(rsum, 32, 64);
    if (lane < 16) rsp[((size_t)sp*NHEAD + h)*NTOK + i0 + li] = rsum;
    __syncthreads();
    float* xw = (float*)Ks + w*(16*68);
    #pragma unroll
    for (int mf=0; mf<4; mf++)
      *(f32x4*)&xw[li*68 + mf*16 + g*4] = xacc[mf];
    __builtin_amdgcn_s_waitcnt(0);
    float xv[16];
    #pragma unroll
    for (int r=0; r<16; r++) xv[r] = xw[r*68 + lane];
    u16x8 o0, o1;
    #pragma unroll
    for (int r=0; r<8; r++){ o0[r] = f2bf(xv[r]); o1[r] = f2bf(xv[8+r]); }
    ushort_t* xp = Xpt + (((size_t)sp*NHEAD + h)*DKH + lane)*NTOK + i0;
    *(u16x8*)(xp)     = o0;
    *(u16x8*)(xp + 8) = o1;
    mark_done(bar + 1);
    return;
  }
  // ================= back (R13 k_back2 verbatim), gated on c1 =================
  {
    wait_for(bar + 1, 256u);
    ushort_t* Ab = (ushort_t*)smem;                 // [8][520] = 8320 B
    float*    Y  = (float*)(smem + 8320);           // [8][516] = 16512 B
    float*    red= (float*)(smem + 24832);          // [8][8][2] = 512 B
    const int m0 = (b - 1536)*8;
    {
      const int n = m0 + w;
      const int h = n >> 7, dk = (n >> 1) & 63, mo = (n & 1)*512;
      float x[8];
      float sum = 0.f, sq = 0.f;
      #pragma unroll
      for (int c=0; c<8; c++){
        int d = c*64 + lane;
        int i = mo + d;
        float sv = 0.f, rv = 0.f;
        #pragma unroll
        for (int sp=0; sp<NSPLIT; sp++){
          sv += bf2f(Xpt[(((size_t)sp*NHEAD + h)*DKH + dk)*NTOK + i]);
          rv += rsp[((size_t)sp*NHEAD + h)*NTOK + i];
        }
        x[c] = sv/rv + inq[(size_t)n*DMODEL + d];
        sum += x[c]; sq += x[c]*x[c];
      }
      sum = wave_sum_f(sum);
      sq  = wave_sum_f(sq);
      float mean = sum * (1.0f/512.0f);
      float var = sq * (1.0f/512.0f) - mean*mean;
      float rs = rsqrtf(var + 1e-5f);
      #pragma unroll
      for (int c=0; c<8; c++){
        int d = c*64 + lane;
        float y = (x[c]-mean)*rs*ln0g[d] + ln0b[d];
        Y[w*516 + d] = y;
        Ab[w*520 + d] = f2bf(y);
      }
    }
    __syncthreads();
    const int n0 = w*64;
    const ushort_t* ar = Ab + (li & 7)*520 + g*8;
    const ushort_t* wr = Wob + (size_t)(n0+li)*DMODEL + g*8;
    f32x4 acc[4] = {};
    #pragma unroll
    for (int k0=0; k0<DMODEL; k0+=64){
      bf16x8 afa = *(const bf16x8*)(ar + k0);
      bf16x8 afb = *(const bf16x8*)(ar + k0 + 32);
      #pragma unroll
      for (int nf=0; nf<4; nf++){
        const ushort_t* wp = wr + (size_t)nf*16*DMODEL + k0;
        bf16x8 wfa = *(const bf16x8*)(wp);
        bf16x8 wfb = *(const bf16x8*)(wp + 32);
        acc[nf] = __builtin_amdgcn_mfma_f32_16x16x32_bf16(wfa, afa, acc[nf], 0,0,0);
        acc[nf] = __builtin_amdgcn_mfma_f32_16x16x32_bf16(wfb, afb, acc[nf], 0,0,0);
      }
    }
    float s = 0.f, qq = 0.f;
    f32x4 v[4];
    #pragma unroll
    for (int nf=0; nf<4; nf++){
      int n = n0 + nf*16 + g*4;
      f32x4 b4 = *(const f32x4*)(bo + n);
      #pragma unroll
      for (int r=0; r<4; r++){
        float x = acc[nf][r] + b4[r] + Y[(li & 7)*516 + n + r];
        v[nf][r] = x; s += x; qq += x*x;
      }
    }
    s  += __shfl_xor(s, 16, 64);  s  += __shfl_xor(s, 32, 64);
    qq += __shfl_xor(qq, 16, 64); qq += __shfl_xor(qq, 32, 64);
    if (g == 0 && li < 8){ red[(w*8 + li)*2] = s; red[(w*8 + li)*2 + 1] = qq; }
    __syncthreads();
    float S = 0.f, Q = 0.f;
    #pragma unroll
    for (int u=0; u<8; u++){ S += red[(u*8 + (li & 7))*2]; Q += red[(u*8 + (li & 7))*2 + 1]; }
    float mean = S * (1.0f/512.0f);
    float var = Q * (1.0f/512.0f) - mean*mean;
    float rs = rsqrtf(var + 1e-5f);
    if (li < 8){
      const int m = m0 + li;
      #pragma unroll
      for (int nf=0; nf<4; nf++){
        int n = n0 + nf*16 + g*4;
        f32x4 g4 = *(const f32x4*)(lng + n);
        f32x4 be = *(const f32x4*)(lnb + n);
        f32x4 o;
        #pragma unroll
        for (int r=0; r<4; r++) o[r] = (v[nf][r]-mean)*rs*g4[r] + be[r];
        *(f32x4*)(out + (size_t)m*DMODEL + n) = o;
      }
    }
  }
}

extern "C" void kernel_launch(void* const* d_in, const int* in_sizes, int n_in,
                              void* d_out, int out_size, void* d_ws, size_t ws_size,
                              hipStream_t stream){
  (void)in_sizes; (void)n_in; (void)out_size; (void)ws_size;
  const float* in_q = (const float*)d_in[0];
  const float* in_k = (const float*)d_in[1];
  const float* in_v = (const float*)d_in[2];
  const float* box  = (const float*)d_in[3];
  const float* Wq   = (const float*)d_in[4];
  const float* bq   = (const float*)d_in[5];
  const float* Wk   = (const float*)d_in[6];
  const float* bk   = (const float*)d_in[7];
  const float* Wv   = (const float*)d_in[8];
  const float* bv   = (const float*)d_in[9];
  const float* Wo   = (const float*)d_in[10];
  const float* bo   = (const float*)d_in[11];
  const float* WGw  = (const float*)d_in[12];
  const float* WGb  = (const float*)d_in[13];
  const float* ln0g = (const float*)d_in[14];
  const float* ln0b = (const float*)d_in[15];
  const float* lng  = (const float*)d_in[16];
  const float* lnb  = (const float*)d_in[17];

  float* ws = (float*)d_ws;
  ushort_t* Wob  = (ushort_t*)(ws + 0);             // [512][512] bf16
  ushort_t* Qb   = (ushort_t*)(ws + 131072);        // [1024][512] bf16
  ushort_t* Kb   = (ushort_t*)(ws + 393216);
  ushort_t* Vt   = (ushort_t*)(ws + 655360);        // [8][64][1024] bf16
  _Float16* wg16 = (_Float16*)(ws + 917504);        // [8][1024][1024] fp16 (16 MB)
  ushort_t* Xpt  = (ushort_t*)(ws + 5111808);       // [4][8][64][1024] bf16 (4 MB)
  float*    rsp  = ws + 6160384;                    // [4][8][1024]
  unsigned* bar  = (unsigned*)(ws + 6193152);       // c0, c1
  float*    out  = (float*)d_out;

  hipMemsetAsync(bar, 0, 8, stream);
  k_all<<<dim3(1664), dim3(512), 0, stream>>>(
      box, WGw, WGb, wg16,
      in_q, in_k, in_v, Wq, Wk, Wv, Wo,
      bq, bk, bv, Qb, Kb, Vt, Wob,
      Xpt, rsp, ln0g, ln0b, bo, lng, lnb, out, bar);
}

// Round 15
// 94.219 us; speedup vs baseline: 2.7363x; 2.7363x over previous
//
#include <hip/hip_runtime.h>
#include <cstddef>

#define NTOK 1024
#define DMODEL 512
#define NHEAD 8
#define DKH 64
#define NSPLIT 4
#define JQ 256

typedef __attribute__((ext_vector_type(4))) float f32x4;
typedef __attribute__((ext_vector_type(8))) __bf16 bf16x8;
typedef __attribute__((ext_vector_type(4))) __bf16 bf16x4;
typedef __attribute__((ext_vector_type(4))) unsigned short u16x4;
typedef __attribute__((ext_vector_type(8))) unsigned short u16x8;
typedef __attribute__((ext_vector_type(4))) _Float16 f16x4;
typedef unsigned short ushort_t;

__device__ __forceinline__ float wave_sum_f(float v){
  #pragma unroll
  for (int m=1; m<64; m<<=1) v += __shfl_xor(v, m, 64);
  return v;
}
__device__ __forceinline__ unsigned short f2bf(float f){
  __bf16 b = (__bf16)f;
  return __builtin_bit_cast(unsigned short, b);
}
__device__ __forceinline__ float bf2f(unsigned short u){
  return (float)__builtin_bit_cast(__bf16, u);
}

// ---- native transcendental ops ----
__device__ __forceinline__ float fract_hw(float x){
  float r; asm("v_fract_f32 %0, %1" : "=v"(r) : "v"(x)); return r;
}
__device__ __forceinline__ float sin_rev(float rev){
  float f = fract_hw(rev);
  float s; asm("v_sin_f32 %0, %1" : "=v"(s) : "v"(f)); return s;
}
__device__ __forceinline__ float cos_rev(float rev){
  float f = fract_hw(rev);
  float c; asm("v_cos_f32 %0, %1" : "=v"(c) : "v"(f)); return c;
}
__device__ __forceinline__ float log_hw(float x){
  float l; asm("v_log_f32 %0, %1" : "=v"(l) : "v"(x));
  return 0.69314718056f * l;
}
__device__ __forceinline__ float exp_hw(float x){
  float y = x * 1.44269504f;
  float e; asm("v_exp_f32 %0, %1" : "=v"(e) : "v"(y));
  return e;
}

__device__ __forceinline__ void mark_done(unsigned* c){
  __syncthreads();
  if (threadIdx.x == 0)
    __hip_atomic_fetch_add(c, 1u, __ATOMIC_RELEASE, __HIP_MEMORY_SCOPE_AGENT);
}
__device__ __forceinline__ void wait_for(unsigned* c, unsigned target){
  if (threadIdx.x == 0){
    while (__hip_atomic_load(c, __ATOMIC_ACQUIRE, __HIP_MEMORY_SCOPE_AGENT) < target)
      __builtin_amdgcn_s_sleep(8);
  }
  __syncthreads();
}

// ================= k_front2: gate (0..1023) | QKV inline-cvt LDS-GEMM (1024..1407) | Wo cvt (1408..1535) ====
// R13 verbatim.
__global__ __launch_bounds__(256) void k_front2(
    const float* __restrict__ box, const float* __restrict__ WGw, const float* __restrict__ WGb,
    _Float16* __restrict__ wg16,
    const float* __restrict__ inq, const float* __restrict__ ink, const float* __restrict__ inv,
    const float* __restrict__ Wq, const float* __restrict__ Wk, const float* __restrict__ Wv,
    const float* __restrict__ Wo,
    const float* __restrict__ bq, const float* __restrict__ bk, const float* __restrict__ bv,
    ushort_t* __restrict__ Qb, ushort_t* __restrict__ Kb, ushort_t* __restrict__ Vt,
    ushort_t* __restrict__ Wob){
  __shared__ __align__(16) char smem[17408];
  const int t = threadIdx.x;
  const int lane = t & 63, w = t >> 6, li = lane & 15, g = lane >> 4;
  if (blockIdx.x >= 1408){
    int off = ((blockIdx.x - 1408)*256 + t)*8;
    float4 a = *(const float4*)(Wo + off);
    float4 b4 = *(const float4*)(Wo + off + 4);
    u16x4 o0, o1;
    o0[0]=f2bf(a.x); o0[1]=f2bf(a.y); o0[2]=f2bf(a.z); o0[3]=f2bf(a.w);
    o1[0]=f2bf(b4.x); o1[1]=f2bf(b4.y); o1[2]=f2bf(b4.z); o1[3]=f2bf(b4.w);
    *(u16x4*)(Wob + off) = o0;
    *(u16x4*)(Wob + off + 4) = o1;
    return;
  }
  if (blockIdx.x >= 1024){
    const int u = blockIdx.x - 1024;
    const int z = u >> 7;
    const int rem = u & 127;
    const int m0 = (rem >> 3)*64;
    const int n0 = (rem & 7)*64;
    const float* A = z==0 ? inq : z==1 ? ink : inv;
    const float* W = z==0 ? Wq : z==1 ? Wk : Wv;
    const float* bias = z==0 ? bq : z==1 ? bk : bv;
    ushort_t* Al = (ushort_t*)smem;            // [64][68]
    ushort_t* Wl = (ushort_t*)(smem + 8704);   // [64][68]
    const int row = t >> 2, kq = (t & 3)*16;
    const int mrb = (w >> 1)*32;
    const int nrb = (w & 1)*32;
    f32x4 acc[2][2] = {};
    for (int k0 = 0; k0 < DMODEL; k0 += 64){
      {
        const float* ap = A + (size_t)(m0+row)*DMODEL + k0 + kq;
        const float* wp = W + (size_t)(n0+row)*DMODEL + k0 + kq;
        #pragma unroll
        for (int q=0; q<4; q++){
          float4 av = *(const float4*)(ap + q*4);
          float4 wv = *(const float4*)(wp + q*4);
          u16x4 pa, pw;
          pa[0]=f2bf(av.x); pa[1]=f2bf(av.y); pa[2]=f2bf(av.z); pa[3]=f2bf(av.w);
          pw[0]=f2bf(wv.x); pw[1]=f2bf(wv.y); pw[2]=f2bf(wv.z); pw[3]=f2bf(wv.w);
          *(u16x4*)(Al + row*68 + kq + q*4) = pa;
          *(u16x4*)(Wl + row*68 + kq + q*4) = pw;
        }
      }
      __syncthreads();
      #pragma unroll
      for (int kc=0; kc<64; kc+=32){
        const ushort_t* arl = Al + (mrb + li)*68 + kc + g*8;
        const ushort_t* wrl = Wl + (nrb + li)*68 + kc + g*8;
        bf16x8 af0 = *(const bf16x8*)(arl);
        bf16x8 af1 = *(const bf16x8*)(arl + 16*68);
        bf16x8 wf0 = *(const bf16x8*)(wrl);
        bf16x8 wf1 = *(const bf16x8*)(wrl + 16*68);
        if (z < 2){
          acc[0][0] = __builtin_amdgcn_mfma_f32_16x16x32_bf16(wf0, af0, acc[0][0], 0,0,0);
          acc[0][1] = __builtin_amdgcn_mfma_f32_16x16x32_bf16(wf0, af1, acc[0][1], 0,0,0);
          acc[1][0] = __builtin_amdgcn_mfma_f32_16x16x32_bf16(wf1, af0, acc[1][0], 0,0,0);
          acc[1][1] = __builtin_amdgcn_mfma_f32_16x16x32_bf16(wf1, af1, acc[1][1], 0,0,0);
        } else {
          acc[0][0] = __builtin_amdgcn_mfma_f32_16x16x32_bf16(af0, wf0, acc[0][0], 0,0,0);
          acc[0][1] = __builtin_amdgcn_mfma_f32_16x16x32_bf16(af0, wf1, acc[0][1], 0,0,0);
          acc[1][0] = __builtin_amdgcn_mfma_f32_16x16x32_bf16(af1, wf0, acc[1][0], 0,0,0);
          acc[1][1] = __builtin_amdgcn_mfma_f32_16x16x32_bf16(af1, wf1, acc[1][1], 0,0,0);
        }
      }
      __syncthreads();
    }
    if (z < 2){
      ushort_t* C = z ? Kb : Qb;
      #pragma unroll
      for (int nf=0; nf<2; nf++){
        int n = n0 + nrb + nf*16 + g*4;
        float4 b4 = *(const float4*)(bias + n);
        const float* bp = (const float*)&b4;
        #pragma unroll
        for (int mf=0; mf<2; mf++){
          int m = m0 + mrb + mf*16 + li;
          u16x4 o;
          #pragma unroll
          for (int r=0; r<4; r++) o[r] = f2bf(acc[nf][mf][r] + bp[r]);
          *(u16x4*)(C + (size_t)m*DMODEL + n) = o;
        }
      }
    } else {
      #pragma unroll
      for (int mf=0; mf<2; mf++){
        int m = m0 + mrb + mf*16 + g*4;
        #pragma unroll
        for (int nf=0; nf<2; nf++){
          int n = n0 + nrb + nf*16 + li;
          float bn = bias[n];
          u16x4 o;
          #pragma unroll
          for (int r=0; r<4; r++) o[r] = f2bf(acc[mf][nf][r] + bn);
          *(u16x4*)(Vt + (((size_t)(n>>6))<<16) + ((size_t)(n&63)<<10) + m) = o;
        }
      }
    }
    return;
  }
  // ---- gate blocks ----
  float* arr = (float*)smem;   // [4][1024] floats = 16 KB <= 17408
  #pragma unroll
  for (int u2=0; u2<4; u2++){
    int idx = u2*256 + t;
    float4 b4 = *(const float4*)(box + idx*4);
    arr[idx]        = (b4.x + b4.z)*0.5f;
    arr[1024+idx]   = (b4.y + b4.w)*0.5f;
    arr[2048+idx]   = log_hw(b4.z - b4.x + 1.0f);
    arr[3072+idx]   = log_hw(b4.w - b4.y + 1.0f);
  }
  const int i = blockIdx.x;
  float4 bi = *(const float4*)(box + i*4);
  float wi = bi.z - bi.x + 1.0f, hi = bi.w - bi.y + 1.0f;
  float Pi = (g==0) ? (bi.x+bi.z)*0.5f : (g==1) ? (bi.y+bi.w)*0.5f
           : (g==2) ? log_hw(wi) : log_hw(hi);
  float Ri = (g==0) ? 1.0f/wi : (g==1) ? 1.0f/hi : 1.0f;
  const bool doLog = (g < 2);
  bf16x8 wfs = {}, wfc = {};
  float wgb_li = 0.0f;
  if (li < 8){
    #pragma unroll
    for (int e=0; e<8; e++){
      wfs[e] = (__bf16)WGw[li*64 + g*8 + e];
      wfc[e] = (__bf16)WGw[li*64 + 32 + g*8 + e];
    }
    wgb_li = WGb[li];
  }
  __syncthreads();
  const float* parr = arr + g*1024;
  const float DMrev[8] = {15.9154943f, 6.7115094f, 2.8302196f, 1.1934938f,
                          0.5032921f, 0.2122365f, 0.08949941f, 0.0377416f};
  const int jbeg = w*256;
  for (int it=0; it<16; ++it){
    int j = jbeg + it*16 + li;
    float diff = (Pi - parr[j])*Ri;
    float lg = log_hw(fmaxf(fabsf(diff), 1e-3f));
    float dv = doLog ? lg : diff;
    bf16x8 afs, afc;
    #pragma unroll
    for (int e=0; e<8; e++){
      float rev = dv * DMrev[e];
      afs[e] = (__bf16)sin_rev(rev);
      afc[e] = (__bf16)cos_rev(rev);
    }
    f32x4 acc = (f32x4){0.f,0.f,0.f,0.f};
    acc = __builtin_amdgcn_mfma_f32_16x16x32_bf16(afs, wfs, acc, 0,0,0);
    acc = __builtin_amdgcn_mfma_f32_16x16x32_bf16(afc, wfc, acc, 0,0,0);
    if (li < 8){
      f16x4 o;
      #pragma unroll
      for (int r=0; r<4; r++)
        o[r] = (_Float16)fmaxf(acc[r] + wgb_li, 6.103515625e-05f);
      *(f16x4*)(wg16 + (((size_t)li<<20) + ((size_t)i<<10) + jbeg + it*16 + g*4)) = o;
    }
  }
}

// ================= k_ab: attn (blocks 0..255) + back (blocks 256..383), flag-gated =================
// ALL 384 blocks co-resident by capacity: 68.6KB LDS -> 2 blocks/CU -> 512 slots >= 384.
// attn/back bodies are R13-verbatim; back waits for all 256 attn blocks via device-scope counter.
__global__ __launch_bounds__(512) void k_ab(const ushort_t* __restrict__ Qb,
     const ushort_t* __restrict__ Kb, const ushort_t* __restrict__ Vt,
     const _Float16* __restrict__ wg, ushort_t* __restrict__ Xpt, float* __restrict__ rsp,
     const float* __restrict__ inq,
     const float* __restrict__ ln0g, const float* __restrict__ ln0b,
     const ushort_t* __restrict__ Wob, const float* __restrict__ bo,
     const float* __restrict__ lng, const float* __restrict__ lnb,
     float* __restrict__ out, unsigned* bar){
  __shared__ __align__(16) char smem[68608];
  const int t = threadIdx.x;
  const int b = blockIdx.x;
  const int lane = t & 63, w = t >> 6, li = lane & 15, g = lane >> 4;

  if (b < 256){
    // ---------------- attn ----------------
    ushort_t* Ks = (ushort_t*)smem;            // [256][68] = 34816 B
    ushort_t* Vs = (ushort_t*)(smem + 34816);  // [64][264] = 33792 B
    const int itg = b & 7, h = (b >> 3) & 7, sp = b >> 6;
    const int jbeg = sp*JQ;
    {
      const int r = t >> 3, c = (t & 7)*8;
      #pragma unroll
      for (int p=0; p<4; p++){
        u16x8 kv = *(const u16x8*)(Kb + (size_t)(jbeg + p*64 + r)*DMODEL + h*DKH + c);
        *(u16x8*)(Ks + (p*64 + r)*68 + c) = kv;
        u16x8 vv = *(const u16x8*)(Vt + ((size_t)h<<16) + (size_t)r*NTOK + jbeg + p*64 + c);
        *(u16x8*)(Vs + r*264 + p*64 + c) = vv;
      }
    }
    const int i0 = (itg*8 + w)*16;
    const ushort_t* qp = Qb + (size_t)(i0+li)*DMODEL + h*DKH + g*8;
    bf16x8 qf0 = *(const bf16x8*)(qp);
    bf16x8 qf1 = *(const bf16x8*)(qp + 32);
    const _Float16* gbase = wg + ((size_t)h<<20) + ((size_t)(i0+li)<<10) + jbeg + g*4;
    f32x4 xacc[4];
    #pragma unroll
    for (int mf=0; mf<4; mf++) xacc[mf] = (f32x4){0.f,0.f,0.f,0.f};
    float rsum = 0.f;
    __syncthreads();
    #pragma unroll
    for (int jj = 0; jj < JQ; jj += 32){
      const ushort_t* kp = Ks + (jj + li)*68 + g*8;
      bf16x8 a00 = *(const bf16x8*)(kp);
      bf16x8 a01 = *(const bf16x8*)(kp + 32);
      bf16x8 a10 = *(const bf16x8*)(kp + 16*68);
      bf16x8 a11 = *(const bf16x8*)(kp + 16*68 + 32);
      f32x4 s0 = (f32x4){0.f,0.f,0.f,0.f};
      f32x4 s1 = (f32x4){0.f,0.f,0.f,0.f};
      s0 = __builtin_amdgcn_mfma_f32_16x16x32_bf16(a00, qf0, s0, 0,0,0);
      s0 = __builtin_amdgcn_mfma_f32_16x16x32_bf16(a01, qf1, s0, 0,0,0);
      s1 = __builtin_amdgcn_mfma_f32_16x16x32_bf16(a10, qf0, s1, 0,0,0);
      s1 = __builtin_amdgcn_mfma_f32_16x16x32_bf16(a11, qf1, s1, 0,0,0);
      f16x4 g0 = *(const f16x4*)(gbase + jj);
      f16x4 g1 = *(const f16x4*)(gbase + jj + 16);
      float p[8];
      #pragma unroll
      for (int r=0; r<4; r++){ p[r]   = (float)g0[r] * exp_hw(s0[r]*0.125f); rsum += p[r]; }
      #pragma unroll
      for (int r=0; r<4; r++){ p[4+r] = (float)g1[r] * exp_hw(s1[r]*0.125f); rsum += p[4+r]; }
      bf16x8 pb;
      pb[0]=(__bf16)p[0]; pb[1]=(__bf16)p[1]; pb[2]=(__bf16)p[2]; pb[3]=(__bf16)p[3];
      pb[4]=(__bf16)p[4]; pb[5]=(__bf16)p[5]; pb[6]=(__bf16)p[6]; pb[7]=(__bf16)p[7];
      #pragma unroll
      for (int mf=0; mf<4; mf++){
        const ushort_t* vp = Vs + (size_t)(li + mf*16)*264 + jj + g*4;
        bf16x4 lo = *(const bf16x4*)(vp);
        bf16x4 hi = *(const bf16x4*)(vp + 16);
        bf16x8 vf = __builtin_shufflevector(lo, hi, 0,1,2,3,4,5,6,7);
        xacc[mf] = __builtin_amdgcn_mfma_f32_16x16x32_bf16(vf, pb, xacc[mf], 0,0,0);
      }
    }
    rsum += __shfl_xor(rsum, 16, 64);
    rsum += __shfl_xor(rsum, 32, 64);
    if (lane < 16) rsp[((size_t)sp*NHEAD + h)*NTOK + i0 + li] = rsum;
    __syncthreads();
    float* xw = (float*)Ks + w*(16*68);
    #pragma unroll
    for (int mf=0; mf<4; mf++)
      *(f32x4*)&xw[li*68 + mf*16 + g*4] = xacc[mf];
    __builtin_amdgcn_s_waitcnt(0);
    float xv[16];
    #pragma unroll
    for (int r=0; r<16; r++) xv[r] = xw[r*68 + lane];
    u16x8 o0, o1;
    #pragma unroll
    for (int r=0; r<8; r++){ o0[r] = f2bf(xv[r]); o1[r] = f2bf(xv[8+r]); }
    ushort_t* xp = Xpt + (((size_t)sp*NHEAD + h)*DKH + lane)*NTOK + i0;
    *(u16x8*)(xp)     = o0;
    *(u16x8*)(xp + 8) = o1;
    mark_done(bar);
    return;
  }
  // ---------------- back ----------------
  {
    wait_for(bar, 256u);
    ushort_t* Ab = (ushort_t*)smem;                 // [8][520]
    float*    Y  = (float*)(smem + 8320);           // [8][516]
    float*    red= (float*)(smem + 24832);          // [8][8][2]
    const int m0 = (b - 256)*8;
    {
      const int n = m0 + w;
      const int h = n >> 7, dk = (n >> 1) & 63, mo = (n & 1)*512;
      float x[8];
      float sum = 0.f, sq = 0.f;
      #pragma unroll
      for (int c=0; c<8; c++){
        int d = c*64 + lane;
        int i = mo + d;
        float sv = 0.f, rv = 0.f;
        #pragma unroll
        for (int sp=0; sp<NSPLIT; sp++){
          sv += bf2f(Xpt[(((size_t)sp*NHEAD + h)*DKH + dk)*NTOK + i]);
          rv += rsp[((size_t)sp*NHEAD + h)*NTOK + i];
        }
        x[c] = sv/rv + inq[(size_t)n*DMODEL + d];
        sum += x[c]; sq += x[c]*x[c];
      }
      sum = wave_sum_f(sum);
      sq  = wave_sum_f(sq);
      float mean = sum * (1.0f/512.0f);
      float var = sq * (1.0f/512.0f) - mean*mean;
      float rs = rsqrtf(var + 1e-5f);
      #pragma unroll
      for (int c=0; c<8; c++){
        int d = c*64 + lane;
        float y = (x[c]-mean)*rs*ln0g[d] + ln0b[d];
        Y[w*516 + d] = y;
        Ab[w*520 + d] = f2bf(y);
      }
    }
    __syncthreads();
    const int n0 = w*64;
    const ushort_t* ar = Ab + (li & 7)*520 + g*8;
    const ushort_t* wr = Wob + (size_t)(n0+li)*DMODEL + g*8;
    f32x4 acc[4] = {};
    #pragma unroll
    for (int k0=0; k0<DMODEL; k0+=64){
      bf16x8 afa = *(const bf16x8*)(ar + k0);
      bf16x8 afb = *(const bf16x8*)(ar + k0 + 32);
      #pragma unroll
      for (int nf=0; nf<4; nf++){
        const ushort_t* wp = wr + (size_t)nf*16*DMODEL + k0;
        bf16x8 wfa = *(const bf16x8*)(wp);
        bf16x8 wfb = *(const bf16x8*)(wp + 32);
        acc[nf] = __builtin_amdgcn_mfma_f32_16x16x32_bf16(wfa, afa, acc[nf], 0,0,0);
        acc[nf] = __builtin_amdgcn_mfma_f32_16x16x32_bf16(wfb, afb, acc[nf], 0,0,0);
      }
    }
    float s = 0.f, qq = 0.f;
    f32x4 v[4];
    #pragma unroll
    for (int nf=0; nf<4; nf++){
      int n = n0 + nf*16 + g*4;
      f32x4 b4 = *(const f32x4*)(bo + n);
      #pragma unroll
      for (int r=0; r<4; r++){
        float x = acc[nf][r] + b4[r] + Y[(li & 7)*516 + n + r];
        v[nf][r] = x; s += x; qq += x*x;
      }
    }
    s  += __shfl_xor(s, 16, 64);  s  += __shfl_xor(s, 32, 64);
    qq += __shfl_xor(qq, 16, 64); qq += __shfl_xor(qq, 32, 64);
    if (g == 0 && li < 8){ red[(w*8 + li)*2] = s; red[(w*8 + li)*2 + 1] = qq; }
    __syncthreads();
    float S = 0.f, Q = 0.f;
    #pragma unroll
    for (int u=0; u<8; u++){ S += red[(u*8 + (li & 7))*2]; Q += red[(u*8 + (li & 7))*2 + 1]; }
    float mean = S * (1.0f/512.0f);
    float var = Q * (1.0f/512.0f) - mean*mean;
    float rs = rsqrtf(var + 1e-5f);
    if (li < 8){
      const int m = m0 + li;
      #pragma unroll
      for (int nf=0; nf<4; nf++){
        int n = n0 + nf*16 + g*4;
        f32x4 g4 = *(const f32x4*)(lng + n);
        f32x4 be = *(const f32x4*)(lnb + n);
        f32x4 o;
        #pragma unroll
        for (int r=0; r<4; r++) o[r] = (v[nf][r]-mean)*rs*g4[r] + be[r];
        *(f32x4*)(out + (size_t)m*DMODEL + n) = o;
      }
    }
  }
}

extern "C" void kernel_launch(void* const* d_in, const int* in_sizes, int n_in,
                              void* d_out, int out_size, void* d_ws, size_t ws_size,
                              hipStream_t stream){
  (void)in_sizes; (void)n_in; (void)out_size; (void)ws_size;
  const float* in_q = (const float*)d_in[0];
  const float* in_k = (const float*)d_in[1];
  const float* in_v = (const float*)d_in[2];
  const float* box  = (const float*)d_in[3];
  const float* Wq   = (const float*)d_in[4];
  const float* bq   = (const float*)d_in[5];
  const float* Wk   = (const float*)d_in[6];
  const float* bk   = (const float*)d_in[7];
  const float* Wv   = (const float*)d_in[8];
  const float* bv   = (const float*)d_in[9];
  const float* Wo   = (const float*)d_in[10];
  const float* bo   = (const float*)d_in[11];
  const float* WGw  = (const float*)d_in[12];
  const float* WGb  = (const float*)d_in[13];
  const float* ln0g = (const float*)d_in[14];
  const float* ln0b = (const float*)d_in[15];
  const float* lng  = (const float*)d_in[16];
  const float* lnb  = (const float*)d_in[17];

  float* ws = (float*)d_ws;
  ushort_t* Wob  = (ushort_t*)(ws + 0);             // [512][512] bf16
  ushort_t* Qb   = (ushort_t*)(ws + 131072);        // [1024][512] bf16
  ushort_t* Kb   = (ushort_t*)(ws + 393216);
  ushort_t* Vt   = (ushort_t*)(ws + 655360);        // [8][64][1024] bf16
  _Float16* wg16 = (_Float16*)(ws + 917504);        // [8][1024][1024] fp16 (16 MB)
  ushort_t* Xpt  = (ushort_t*)(ws + 5111808);       // [4][8][64][1024] bf16 (4 MB)
  float*    rsp  = ws + 6160384;                    // [4][8][1024]
  unsigned* bar  = (unsigned*)(ws + 6193152);
  float*    out  = (float*)d_out;

  hipMemsetAsync(bar, 0, 8, stream);
  k_front2<<<dim3(1536), dim3(256), 0, stream>>>(box, WGw, WGb, wg16,
            in_q, in_k, in_v, Wq, Wk, Wv, Wo, bq, bk, bv, Qb, Kb, Vt, Wob);
  k_ab<<<dim3(384), dim3(512), 0, stream>>>(Qb, Kb, Vt, wg16, Xpt, rsp,
            in_q, ln0g, ln0b, Wob, bo, lng, lnb, out, bar);
}

// Round 16
// 92.347 us; speedup vs baseline: 2.7918x; 1.0203x over previous
//
#include <hip/hip_runtime.h>
#include <cstddef>

#define NTOK 1024
#define DMODEL 512
#define NHEAD 8
#define DKH 64
#define NSPLIT 4
#define JQ 256

typedef __attribute__((ext_vector_type(4))) float f32x4;
typedef __attribute__((ext_vector_type(8))) __bf16 bf16x8;
typedef __attribute__((ext_vector_type(4))) __bf16 bf16x4;
typedef __attribute__((ext_vector_type(4))) unsigned short u16x4;
typedef __attribute__((ext_vector_type(8))) unsigned short u16x8;
typedef __attribute__((ext_vector_type(4))) _Float16 f16x4;
typedef unsigned short ushort_t;

__device__ __forceinline__ float wave_sum_f(float v){
  #pragma unroll
  for (int m=1; m<64; m<<=1) v += __shfl_xor(v, m, 64);
  return v;
}
__device__ __forceinline__ unsigned short f2bf(float f){
  __bf16 b = (__bf16)f;
  return __builtin_bit_cast(unsigned short, b);
}
__device__ __forceinline__ float bf2f(unsigned short u){
  return (float)__builtin_bit_cast(__bf16, u);
}

// ---- native transcendental ops ----
__device__ __forceinline__ float fract_hw(float x){
  float r; asm("v_fract_f32 %0, %1" : "=v"(r) : "v"(x)); return r;
}
__device__ __forceinline__ float sin_rev(float rev){
  float f = fract_hw(rev);
  float s; asm("v_sin_f32 %0, %1" : "=v"(s) : "v"(f)); return s;
}
__device__ __forceinline__ float cos_rev(float rev){
  float f = fract_hw(rev);
  float c; asm("v_cos_f32 %0, %1" : "=v"(c) : "v"(f)); return c;
}
__device__ __forceinline__ float log_hw(float x){
  float l; asm("v_log_f32 %0, %1" : "=v"(l) : "v"(x));
  return 0.69314718056f * l;
}
__device__ __forceinline__ float exp_hw(float x){
  float y = x * 1.44269504f;
  float e; asm("v_exp_f32 %0, %1" : "=v"(e) : "v"(y));
  return e;
}

__device__ __forceinline__ void mark_done(unsigned* c){
  __syncthreads();
  if (threadIdx.x == 0)
    __hip_atomic_fetch_add(c, 1u, __ATOMIC_RELEASE, __HIP_MEMORY_SCOPE_AGENT);
}
// RELAXED poll (no per-iteration cache invalidation!) + ONE acquire load at exit.
__device__ __forceinline__ void wait_for(unsigned* c, unsigned target){
  if (threadIdx.x == 0){
    while (__hip_atomic_load(c, __ATOMIC_RELAXED, __HIP_MEMORY_SCOPE_AGENT) < target)
      __builtin_amdgcn_s_sleep(16);
    (void)__hip_atomic_load(c, __ATOMIC_ACQUIRE, __HIP_MEMORY_SCOPE_AGENT);
  }
  __syncthreads();
}

// ================= k_front2: gate (0..1023) | QKV inline-cvt LDS-GEMM (1024..1407) | Wo cvt (1408..1535) ====
__global__ __launch_bounds__(256) void k_front2(
    const float* __restrict__ box, const float* __restrict__ WGw, const float* __restrict__ WGb,
    _Float16* __restrict__ wg16,
    const float* __restrict__ inq, const float* __restrict__ ink, const float* __restrict__ inv,
    const float* __restrict__ Wq, const float* __restrict__ Wk, const float* __restrict__ Wv,
    const float* __restrict__ Wo,
    const float* __restrict__ bq, const float* __restrict__ bk, const float* __restrict__ bv,
    ushort_t* __restrict__ Qb, ushort_t* __restrict__ Kb, ushort_t* __restrict__ Vt,
    ushort_t* __restrict__ Wob){
  __shared__ __align__(16) char smem[17408];
  const int t = threadIdx.x;
  const int lane = t & 63, w = t >> 6, li = lane & 15, g = lane >> 4;
  if (blockIdx.x >= 1408){
    int off = ((blockIdx.x - 1408)*256 + t)*8;
    float4 a = *(const float4*)(Wo + off);
    float4 b4 = *(const float4*)(Wo + off + 4);
    u16x4 o0, o1;
    o0[0]=f2bf(a.x); o0[1]=f2bf(a.y); o0[2]=f2bf(a.z); o0[3]=f2bf(a.w);
    o1[0]=f2bf(b4.x); o1[1]=f2bf(b4.y); o1[2]=f2bf(b4.z); o1[3]=f2bf(b4.w);
    *(u16x4*)(Wob + off) = o0;
    *(u16x4*)(Wob + off + 4) = o1;
    return;
  }
  if (blockIdx.x >= 1024){
    const int u = blockIdx.x - 1024;
    const int z = u >> 7;
    const int rem = u & 127;
    const int m0 = (rem >> 3)*64;
    const int n0 = (rem & 7)*64;
    const float* A = z==0 ? inq : z==1 ? ink : inv;
    const float* W = z==0 ? Wq : z==1 ? Wk : Wv;
    const float* bias = z==0 ? bq : z==1 ? bk : bv;
    ushort_t* Al = (ushort_t*)smem;            // [64][68]
    ushort_t* Wl = (ushort_t*)(smem + 8704);   // [64][68]
    const int row = t >> 2, kq = (t & 3)*16;
    const int mrb = (w >> 1)*32;
    const int nrb = (w & 1)*32;
    f32x4 acc[2][2] = {};
    for (int k0 = 0; k0 < DMODEL; k0 += 64){
      {
        const float* ap = A + (size_t)(m0+row)*DMODEL + k0 + kq;
        const float* wp = W + (size_t)(n0+row)*DMODEL + k0 + kq;
        #pragma unroll
        for (int q=0; q<4; q++){
          float4 av = *(const float4*)(ap + q*4);
          float4 wv = *(const float4*)(wp + q*4);
          u16x4 pa, pw;
          pa[0]=f2bf(av.x); pa[1]=f2bf(av.y); pa[2]=f2bf(av.z); pa[3]=f2bf(av.w);
          pw[0]=f2bf(wv.x); pw[1]=f2bf(wv.y); pw[2]=f2bf(wv.z); pw[3]=f2bf(wv.w);
          *(u16x4*)(Al + row*68 + kq + q*4) = pa;
          *(u16x4*)(Wl + row*68 + kq + q*4) = pw;
        }
      }
      __syncthreads();
      #pragma unroll
      for (int kc=0; kc<64; kc+=32){
        const ushort_t* arl = Al + (mrb + li)*68 + kc + g*8;
        const ushort_t* wrl = Wl + (nrb + li)*68 + kc + g*8;
        bf16x8 af0 = *(const bf16x8*)(arl);
        bf16x8 af1 = *(const bf16x8*)(arl + 16*68);
        bf16x8 wf0 = *(const bf16x8*)(wrl);
        bf16x8 wf1 = *(const bf16x8*)(wrl + 16*68);
        if (z < 2){
          acc[0][0] = __builtin_amdgcn_mfma_f32_16x16x32_bf16(wf0, af0, acc[0][0], 0,0,0);
          acc[0][1] = __builtin_amdgcn_mfma_f32_16x16x32_bf16(wf0, af1, acc[0][1], 0,0,0);
          acc[1][0] = __builtin_amdgcn_mfma_f32_16x16x32_bf16(wf1, af0, acc[1][0], 0,0,0);
          acc[1][1] = __builtin_amdgcn_mfma_f32_16x16x32_bf16(wf1, af1, acc[1][1], 0,0,0);
        } else {
          acc[0][0] = __builtin_amdgcn_mfma_f32_16x16x32_bf16(af0, wf0, acc[0][0], 0,0,0);
          acc[0][1] = __builtin_amdgcn_mfma_f32_16x16x32_bf16(af0, wf1, acc[0][1], 0,0,0);
          acc[1][0] = __builtin_amdgcn_mfma_f32_16x16x32_bf16(af1, wf0, acc[1][0], 0,0,0);
          acc[1][1] = __builtin_amdgcn_mfma_f32_16x16x32_bf16(af1, wf1, acc[1][1], 0,0,0);
        }
      }
      __syncthreads();
    }
    if (z < 2){
      ushort_t* C = z ? Kb : Qb;
      #pragma unroll
      for (int nf=0; nf<2; nf++){
        int n = n0 + nrb + nf*16 + g*4;
        float4 b4 = *(const float4*)(bias + n);
        const float* bp = (const float*)&b4;
        #pragma unroll
        for (int mf=0; mf<2; mf++){
          int m = m0 + mrb + mf*16 + li;
          u16x4 o;
          #pragma unroll
          for (int r=0; r<4; r++) o[r] = f2bf(acc[nf][mf][r] + bp[r]);
          *(u16x4*)(C + (size_t)m*DMODEL + n) = o;
        }
      }
    } else {
      #pragma unroll
      for (int mf=0; mf<2; mf++){
        int m = m0 + mrb + mf*16 + g*4;
        #pragma unroll
        for (int nf=0; nf<2; nf++){
          int n = n0 + nrb + nf*16 + li;
          float bn = bias[n];
          u16x4 o;
          #pragma unroll
          for (int r=0; r<4; r++) o[r] = f2bf(acc[mf][nf][r] + bn);
          *(u16x4*)(Vt + (((size_t)(n>>6))<<16) + ((size_t)(n&63)<<10) + m) = o;
        }
      }
    }
    return;
  }
  // ---- gate blocks ----
  float* arr = (float*)smem;   // [4][1024] floats = 16 KB <= 17408
  #pragma unroll
  for (int u2=0; u2<4; u2++){
    int idx = u2*256 + t;
    float4 b4 = *(const float4*)(box + idx*4);
    arr[idx]        = (b4.x + b4.z)*0.5f;
    arr[1024+idx]   = (b4.y + b4.w)*0.5f;
    arr[2048+idx]   = log_hw(b4.z - b4.x + 1.0f);
    arr[3072+idx]   = log_hw(b4.w - b4.y + 1.0f);
  }
  const int i = blockIdx.x;
  float4 bi = *(const float4*)(box + i*4);
  float wi = bi.z - bi.x + 1.0f, hi = bi.w - bi.y + 1.0f;
  float Pi = (g==0) ? (bi.x+bi.z)*0.5f : (g==1) ? (bi.y+bi.w)*0.5f
           : (g==2) ? log_hw(wi) : log_hw(hi);
  float Ri = (g==0) ? 1.0f/wi : (g==1) ? 1.0f/hi : 1.0f;
  const bool doLog = (g < 2);
  bf16x8 wfs = {}, wfc = {};
  float wgb_li = 0.0f;
  if (li < 8){
    #pragma unroll
    for (int e=0; e<8; e++){
      wfs[e] = (__bf16)WGw[li*64 + g*8 + e];
      wfc[e] = (__bf16)WGw[li*64 + 32 + g*8 + e];
    }
    wgb_li = WGb[li];
  }
  __syncthreads();
  const float* parr = arr + g*1024;
  const float DMrev[8] = {15.9154943f, 6.7115094f, 2.8302196f, 1.1934938f,
                          0.5032921f, 0.2122365f, 0.08949941f, 0.0377416f};
  const int jbeg = w*256;
  for (int it=0; it<16; ++it){
    int j = jbeg + it*16 + li;
    float diff = (Pi - parr[j])*Ri;
    float lg = log_hw(fmaxf(fabsf(diff), 1e-3f));
    float dv = doLog ? lg : diff;
    bf16x8 afs, afc;
    #pragma unroll
    for (int e=0; e<8; e++){
      float rev = dv * DMrev[e];
      afs[e] = (__bf16)sin_rev(rev);
      afc[e] = (__bf16)cos_rev(rev);
    }
    f32x4 acc = (f32x4){0.f,0.f,0.f,0.f};
    acc = __builtin_amdgcn_mfma_f32_16x16x32_bf16(afs, wfs, acc, 0,0,0);
    acc = __builtin_amdgcn_mfma_f32_16x16x32_bf16(afc, wfc, acc, 0,0,0);
    if (li < 8){
      f16x4 o;
      #pragma unroll
      for (int r=0; r<4; r++)
        o[r] = (_Float16)fmaxf(acc[r] + wgb_li, 6.103515625e-05f);
      *(f16x4*)(wg16 + (((size_t)li<<20) + ((size_t)i<<10) + jbeg + it*16 + g*4)) = o;
    }
  }
}

// ================= k_ab: attn (0..255) + back (256..383), relaxed-poll flag gating =================
__global__ __launch_bounds__(512) void k_ab(const ushort_t* __restrict__ Qb,
     const ushort_t* __restrict__ Kb, const ushort_t* __restrict__ Vt,
     const _Float16* __restrict__ wg, ushort_t* __restrict__ Xpt, float* __restrict__ rsp,
     const float* __restrict__ inq,
     const float* __restrict__ ln0g, const float* __restrict__ ln0b,
     const ushort_t* __restrict__ Wob, const float* __restrict__ bo,
     const float* __restrict__ lng, const float* __restrict__ lnb,
     float* __restrict__ out, unsigned* bar){
  __shared__ __align__(16) char smem[68608];
  const int t = threadIdx.x;
  const int b = blockIdx.x;
  const int lane = t & 63, w = t >> 6, li = lane & 15, g = lane >> 4;

  if (b < 256){
    // ---------------- attn ----------------
    ushort_t* Ks = (ushort_t*)smem;            // [256][68]
    ushort_t* Vs = (ushort_t*)(smem + 34816);  // [64][264]
    const int itg = b & 7, h = (b >> 3) & 7, sp = b >> 6;
    const int jbeg = sp*JQ;
    {
      const int r = t >> 3, c = (t & 7)*8;
      #pragma unroll
      for (int p=0; p<4; p++){
        u16x8 kv = *(const u16x8*)(Kb + (size_t)(jbeg + p*64 + r)*DMODEL + h*DKH + c);
        *(u16x8*)(Ks + (p*64 + r)*68 + c) = kv;
        u16x8 vv = *(const u16x8*)(Vt + ((size_t)h<<16) + (size_t)r*NTOK + jbeg + p*64 + c);
        *(u16x8*)(Vs + r*264 + p*64 + c) = vv;
      }
    }
    const int i0 = (itg*8 + w)*16;
    const ushort_t* qp = Qb + (size_t)(i0+li)*DMODEL + h*DKH + g*8;
    bf16x8 qf0 = *(const bf16x8*)(qp);
    bf16x8 qf1 = *(const bf16x8*)(qp + 32);
    const _Float16* gbase = wg + ((size_t)h<<20) + ((size_t)(i0+li)<<10) + jbeg + g*4;
    f32x4 xacc[4];
    #pragma unroll
    for (int mf=0; mf<4; mf++) xacc[mf] = (f32x4){0.f,0.f,0.f,0.f};
    float rsum = 0.f;
    __syncthreads();
    #pragma unroll
    for (int jj = 0; jj < JQ; jj += 32){
      const ushort_t* kp = Ks + (jj + li)*68 + g*8;
      bf16x8 a00 = *(const bf16x8*)(kp);
      bf16x8 a01 = *(const bf16x8*)(kp + 32);
      bf16x8 a10 = *(const bf16x8*)(kp + 16*68);
      bf16x8 a11 = *(const bf16x8*)(kp + 16*68 + 32);
      f32x4 s0 = (f32x4){0.f,0.f,0.f,0.f};
      f32x4 s1 = (f32x4){0.f,0.f,0.f,0.f};
      s0 = __builtin_amdgcn_mfma_f32_16x16x32_bf16(a00, qf0, s0, 0,0,0);
      s0 = __builtin_amdgcn_mfma_f32_16x16x32_bf16(a01, qf1, s0, 0,0,0);
      s1 = __builtin_amdgcn_mfma_f32_16x16x32_bf16(a10, qf0, s1, 0,0,0);
      s1 = __builtin_amdgcn_mfma_f32_16x16x32_bf16(a11, qf1, s1, 0,0,0);
      f16x4 g0 = *(const f16x4*)(gbase + jj);
      f16x4 g1 = *(const f16x4*)(gbase + jj + 16);
      float p[8];
      #pragma unroll
      for (int r=0; r<4; r++){ p[r]   = (float)g0[r] * exp_hw(s0[r]*0.125f); rsum += p[r]; }
      #pragma unroll
      for (int r=0; r<4; r++){ p[4+r] = (float)g1[r] * exp_hw(s1[r]*0.125f); rsum += p[4+r]; }
      bf16x8 pb;
      pb[0]=(__bf16)p[0]; pb[1]=(__bf16)p[1]; pb[2]=(__bf16)p[2]; pb[3]=(__bf16)p[3];
      pb[4]=(__bf16)p[4]; pb[5]=(__bf16)p[5]; pb[6]=(__bf16)p[6]; pb[7]=(__bf16)p[7];
      #pragma unroll
      for (int mf=0; mf<4; mf++){
        const ushort_t* vp = Vs + (size_t)(li + mf*16)*264 + jj + g*4;
        bf16x4 lo = *(const bf16x4*)(vp);
        bf16x4 hi = *(const bf16x4*)(vp + 16);
        bf16x8 vf = __builtin_shufflevector(lo, hi, 0,1,2,3,4,5,6,7);
        xacc[mf] = __builtin_amdgcn_mfma_f32_16x16x32_bf16(vf, pb, xacc[mf], 0,0,0);
      }
    }
    rsum += __shfl_xor(rsum, 16, 64);
    rsum += __shfl_xor(rsum, 32, 64);
    if (lane < 16) rsp[((size_t)sp*NHEAD + h)*NTOK + i0 + li] = rsum;
    __syncthreads();
    float* xw = (float*)Ks + w*(16*68);
    #pragma unroll
    for (int mf=0; mf<4; mf++)
      *(f32x4*)&xw[li*68 + mf*16 + g*4] = xacc[mf];
    __builtin_amdgcn_s_waitcnt(0);
    float xv[16];
    #pragma unroll
    for (int r=0; r<16; r++) xv[r] = xw[r*68 + lane];
    u16x8 o0, o1;
    #pragma unroll
    for (int r=0; r<8; r++){ o0[r] = f2bf(xv[r]); o1[r] = f2bf(xv[8+r]); }
    ushort_t* xp = Xpt + (((size_t)sp*NHEAD + h)*DKH + lane)*NTOK + i0;
    *(u16x8*)(xp)     = o0;
    *(u16x8*)(xp + 8) = o1;
    mark_done(bar);
    return;
  }
  // ---------------- back ----------------
  {
    wait_for(bar, 256u);
    ushort_t* Ab = (ushort_t*)smem;                 // [8][520]
    float*    Y  = (float*)(smem + 8320);           // [8][516]
    float*    red= (float*)(smem + 24832);          // [8][8][2]
    const int m0 = (b - 256)*8;
    {
      const int n = m0 + w;
      const int h = n >> 7, dk = (n >> 1) & 63, mo = (n & 1)*512;
      float x[8];
      float sum = 0.f, sq = 0.f;
      #pragma unroll
      for (int c=0; c<8; c++){
        int d = c*64 + lane;
        int i = mo + d;
        float sv = 0.f, rv = 0.f;
        #pragma unroll
        for (int sp=0; sp<NSPLIT; sp++){
          sv += bf2f(Xpt[(((size_t)sp*NHEAD + h)*DKH + dk)*NTOK + i]);
          rv += rsp[((size_t)sp*NHEAD + h)*NTOK + i];
        }
        x[c] = sv/rv + inq[(size_t)n*DMODEL + d];
        sum += x[c]; sq += x[c]*x[c];
      }
      sum = wave_sum_f(sum);
      sq  = wave_sum_f(sq);
      float mean = sum * (1.0f/512.0f);
      float var = sq * (1.0f/512.0f) - mean*mean;
      float rs = rsqrtf(var + 1e-5f);
      #pragma unroll
      for (int c=0; c<8; c++){
        int d = c*64 + lane;
        float y = (x[c]-mean)*rs*ln0g[d] + ln0b[d];
        Y[w*516 + d] = y;
        Ab[w*520 + d] = f2bf(y);
      }
    }
    __syncthreads();
    const int n0 = w*64;
    const ushort_t* ar = Ab + (li & 7)*520 + g*8;
    const ushort_t* wr = Wob + (size_t)(n0+li)*DMODEL + g*8;
    f32x4 acc[4] = {};
    #pragma unroll
    for (int k0=0; k0<DMODEL; k0+=64){
      bf16x8 afa = *(const bf16x8*)(ar + k0);
      bf16x8 afb = *(const bf16x8*)(ar + k0 + 32);
      #pragma unroll
      for (int nf=0; nf<4; nf++){
        const ushort_t* wp = wr + (size_t)nf*16*DMODEL + k0;
        bf16x8 wfa = *(const bf16x8*)(wp);
        bf16x8 wfb = *(const bf16x8*)(wp + 32);
        acc[nf] = __builtin_amdgcn_mfma_f32_16x16x32_bf16(wfa, afa, acc[nf], 0,0,0);
        acc[nf] = __builtin_amdgcn_mfma_f32_16x16x32_bf16(wfb, afb, acc[nf], 0,0,0);
      }
    }
    float s = 0.f, qq = 0.f;
    f32x4 v[4];
    #pragma unroll
    for (int nf=0; nf<4; nf++){
      int n = n0 + nf*16 + g*4;
      f32x4 b4 = *(const f32x4*)(bo + n);
      #pragma unroll
      for (int r=0; r<4; r++){
        float x = acc[nf][r] + b4[r] + Y[(li & 7)*516 + n + r];
        v[nf][r] = x; s += x; qq += x*x;
      }
    }
    s  += __shfl_xor(s, 16, 64);  s  += __shfl_xor(s, 32, 64);
    qq += __shfl_xor(qq, 16, 64); qq += __shfl_xor(qq, 32, 64);
    if (g == 0 && li < 8){ red[(w*8 + li)*2] = s; red[(w*8 + li)*2 + 1] = qq; }
    __syncthreads();
    float S = 0.f, Q = 0.f;
    #pragma unroll
    for (int u=0; u<8; u++){ S += red[(u*8 + (li & 7))*2]; Q += red[(u*8 + (li & 7))*2 + 1]; }
    float mean = S * (1.0f/512.0f);
    float var = Q * (1.0f/512.0f) - mean*mean;
    float rs = rsqrtf(var + 1e-5f);
    if (li < 8){
      const int m = m0 + li;
      #pragma unroll
      for (int nf=0; nf<4; nf++){
        int n = n0 + nf*16 + g*4;
        f32x4 g4 = *(const f32x4*)(lng + n);
        f32x4 be = *(const f32x4*)(lnb + n);
        f32x4 o;
        #pragma unroll
        for (int r=0; r<4; r++) o[r] = (v[nf][r]-mean)*rs*g4[r] + be[r];
        *(f32x4*)(out + (size_t)m*DMODEL + n) = o;
      }
    }
  }
}

extern "C" void kernel_launch(void* const* d_in, const int* in_sizes, int n_in,
                              void* d_out, int out_size, void* d_ws, size_t ws_size,
                              hipStream_t stream){
  (void)in_sizes; (void)n_in; (void)out_size; (void)ws_size;
  const float* in_q = (const float*)d_in[0];
  const float* in_k = (const float*)d_in[1];
  const float* in_v = (const float*)d_in[2];
  const float* box  = (const float*)d_in[3];
  const float* Wq   = (const float*)d_in[4];
  const float* bq   = (const float*)d_in[5];
  const float* Wk   = (const float*)d_in[6];
  const float* bk   = (const float*)d_in[7];
  const float* Wv   = (const float*)d_in[8];
  const float* bv   = (const float*)d_in[9];
  const float* Wo   = (const float*)d_in[10];
  const float* bo   = (const float*)d_in[11];
  const float* WGw  = (const float*)d_in[12];
  const float* WGb  = (const float*)d_in[13];
  const float* ln0g = (const float*)d_in[14];
  const float* ln0b = (const float*)d_in[15];
  const float* lng  = (const float*)d_in[16];
  const float* lnb  = (const float*)d_in[17];

  float* ws = (float*)d_ws;
  ushort_t* Wob  = (ushort_t*)(ws + 0);             // [512][512] bf16
  ushort_t* Qb   = (ushort_t*)(ws + 131072);        // [1024][512] bf16
  ushort_t* Kb   = (ushort_t*)(ws + 393216);
  ushort_t* Vt   = (ushort_t*)(ws + 655360);        // [8][64][1024] bf16
  _Float16* wg16 = (_Float16*)(ws + 917504);        // [8][1024][1024] fp16 (16 MB)
  ushort_t* Xpt  = (ushort_t*)(ws + 5111808);       // [4][8][64][1024] bf16 (4 MB)
  float*    rsp  = ws + 6160384;                    // [4][8][1024]
  unsigned* bar  = (unsigned*)(ws + 6193152);
  float*    out  = (float*)d_out;

  hipMemsetAsync(bar, 0, 8, stream);
  k_front2<<<dim3(1536), dim3(256), 0, stream>>>(box, WGw, WGb, wg16,
            in_q, in_k, in_v, Wq, Wk, Wv, Wo, bq, bk, bv, Qb, Kb, Vt, Wob);
  k_ab<<<dim3(384), dim3(512), 0, stream>>>(Qb, Kb, Vt, wg16, Xpt, rsp,
            in_q, ln0g, ln0b, Wob, bo, lng, lnb, out, bar);
}

// Round 17
// 66.505 us; speedup vs baseline: 3.8766x; 1.3886x over previous
//
#include <hip/hip_runtime.h>
#include <cstddef>

#define NTOK 1024
#define DMODEL 512
#define NHEAD 8
#define DKH 64
#define NSPLIT 4
#define JQ 256

typedef __attribute__((ext_vector_type(4))) float f32x4;
typedef __attribute__((ext_vector_type(8))) __bf16 bf16x8;
typedef __attribute__((ext_vector_type(4))) __bf16 bf16x4;
typedef __attribute__((ext_vector_type(4))) unsigned short u16x4;
typedef __attribute__((ext_vector_type(8))) unsigned short u16x8;
typedef __attribute__((ext_vector_type(4))) _Float16 f16x4;
typedef unsigned short ushort_t;

__device__ __forceinline__ float wave_sum_f(float v){
  #pragma unroll
  for (int m=1; m<64; m<<=1) v += __shfl_xor(v, m, 64);
  return v;
}
__device__ __forceinline__ unsigned short f2bf(float f){
  __bf16 b = (__bf16)f;
  return __builtin_bit_cast(unsigned short, b);
}
__device__ __forceinline__ float bf2f(unsigned short u){
  return (float)__builtin_bit_cast(__bf16, u);
}

// ---- native transcendental ops ----
__device__ __forceinline__ float fract_hw(float x){
  float r; asm("v_fract_f32 %0, %1" : "=v"(r) : "v"(x)); return r;
}
__device__ __forceinline__ float sin_rev(float rev){
  float f = fract_hw(rev);
  float s; asm("v_sin_f32 %0, %1" : "=v"(s) : "v"(f)); return s;
}
__device__ __forceinline__ float cos_rev(float rev){
  float f = fract_hw(rev);
  float c; asm("v_cos_f32 %0, %1" : "=v"(c) : "v"(f)); return c;
}
__device__ __forceinline__ float log_hw(float x){
  float l; asm("v_log_f32 %0, %1" : "=v"(l) : "v"(x));
  return 0.69314718056f * l;
}
__device__ __forceinline__ float exp_hw(float x){
  float y = x * 1.44269504f;
  float e; asm("v_exp_f32 %0, %1" : "=v"(e) : "v"(y));
  return e;
}

// ================= k_front2: gate (0..1023) | QKV inline-cvt LDS-GEMM (1024..1407) | Wo cvt (1408..1535) ====
__global__ __launch_bounds__(256) void k_front2(
    const float* __restrict__ box, const float* __restrict__ WGw, const float* __restrict__ WGb,
    _Float16* __restrict__ wg16,
    const float* __restrict__ inq, const float* __restrict__ ink, const float* __restrict__ inv,
    const float* __restrict__ Wq, const float* __restrict__ Wk, const float* __restrict__ Wv,
    const float* __restrict__ Wo,
    const float* __restrict__ bq, const float* __restrict__ bk, const float* __restrict__ bv,
    ushort_t* __restrict__ Qb, ushort_t* __restrict__ Kb, ushort_t* __restrict__ Vt,
    ushort_t* __restrict__ Wob){
  __shared__ __align__(16) char smem[17408];
  const int t = threadIdx.x;
  const int lane = t & 63, w = t >> 6, li = lane & 15, g = lane >> 4;
  if (blockIdx.x >= 1408){
    int off = ((blockIdx.x - 1408)*256 + t)*8;
    float4 a = *(const float4*)(Wo + off);
    float4 b4 = *(const float4*)(Wo + off + 4);
    u16x4 o0, o1;
    o0[0]=f2bf(a.x); o0[1]=f2bf(a.y); o0[2]=f2bf(a.z); o0[3]=f2bf(a.w);
    o1[0]=f2bf(b4.x); o1[1]=f2bf(b4.y); o1[2]=f2bf(b4.z); o1[3]=f2bf(b4.w);
    *(u16x4*)(Wob + off) = o0;
    *(u16x4*)(Wob + off + 4) = o1;
    return;
  }
  if (blockIdx.x >= 1024){
    const int u = blockIdx.x - 1024;
    const int z = u >> 7;
    const int rem = u & 127;
    const int m0 = (rem >> 3)*64;
    const int n0 = (rem & 7)*64;
    const float* A = z==0 ? inq : z==1 ? ink : inv;
    const float* W = z==0 ? Wq : z==1 ? Wk : Wv;
    const float* bias = z==0 ? bq : z==1 ? bk : bv;
    ushort_t* Al = (ushort_t*)smem;            // [64][68]
    ushort_t* Wl = (ushort_t*)(smem + 8704);   // [64][68]
    const int row = t >> 2, kq = (t & 3)*16;
    const int mrb = (w >> 1)*32;
    const int nrb = (w & 1)*32;
    f32x4 acc[2][2] = {};
    for (int k0 = 0; k0 < DMODEL; k0 += 64){
      {
        const float* ap = A + (size_t)(m0+row)*DMODEL + k0 + kq;
        const float* wp = W + (size_t)(n0+row)*DMODEL + k0 + kq;
        #pragma unroll
        for (int q=0; q<4; q++){
          float4 av = *(const float4*)(ap + q*4);
          float4 wv = *(const float4*)(wp + q*4);
          u16x4 pa, pw;
          pa[0]=f2bf(av.x); pa[1]=f2bf(av.y); pa[2]=f2bf(av.z); pa[3]=f2bf(av.w);
          pw[0]=f2bf(wv.x); pw[1]=f2bf(wv.y); pw[2]=f2bf(wv.z); pw[3]=f2bf(wv.w);
          *(u16x4*)(Al + row*68 + kq + q*4) = pa;
          *(u16x4*)(Wl + row*68 + kq + q*4) = pw;
        }
      }
      __syncthreads();
      #pragma unroll
      for (int kc=0; kc<64; kc+=32){
        const ushort_t* arl = Al + (mrb + li)*68 + kc + g*8;
        const ushort_t* wrl = Wl + (nrb + li)*68 + kc + g*8;
        bf16x8 af0 = *(const bf16x8*)(arl);
        bf16x8 af1 = *(const bf16x8*)(arl + 16*68);
        bf16x8 wf0 = *(const bf16x8*)(wrl);
        bf16x8 wf1 = *(const bf16x8*)(wrl + 16*68);
        if (z < 2){
          acc[0][0] = __builtin_amdgcn_mfma_f32_16x16x32_bf16(wf0, af0, acc[0][0], 0,0,0);
          acc[0][1] = __builtin_amdgcn_mfma_f32_16x16x32_bf16(wf0, af1, acc[0][1], 0,0,0);
          acc[1][0] = __builtin_amdgcn_mfma_f32_16x16x32_bf16(wf1, af0, acc[1][0], 0,0,0);
          acc[1][1] = __builtin_amdgcn_mfma_f32_16x16x32_bf16(wf1, af1, acc[1][1], 0,0,0);
        } else {
          acc[0][0] = __builtin_amdgcn_mfma_f32_16x16x32_bf16(af0, wf0, acc[0][0], 0,0,0);
          acc[0][1] = __builtin_amdgcn_mfma_f32_16x16x32_bf16(af0, wf1, acc[0][1], 0,0,0);
          acc[1][0] = __builtin_amdgcn_mfma_f32_16x16x32_bf16(af1, wf0, acc[1][0], 0,0,0);
          acc[1][1] = __builtin_amdgcn_mfma_f32_16x16x32_bf16(af1, wf1, acc[1][1], 0,0,0);
        }
      }
      __syncthreads();
    }
    if (z < 2){
      ushort_t* C = z ? Kb : Qb;
      #pragma unroll
      for (int nf=0; nf<2; nf++){
        int n = n0 + nrb + nf*16 + g*4;
        float4 b4 = *(const float4*)(bias + n);
        const float* bp = (const float*)&b4;
        #pragma unroll
        for (int mf=0; mf<2; mf++){
          int m = m0 + mrb + mf*16 + li;
          u16x4 o;
          #pragma unroll
          for (int r=0; r<4; r++) o[r] = f2bf(acc[nf][mf][r] + bp[r]);
          *(u16x4*)(C + (size_t)m*DMODEL + n) = o;
        }
      }
    } else {
      #pragma unroll
      for (int mf=0; mf<2; mf++){
        int m = m0 + mrb + mf*16 + g*4;
        #pragma unroll
        for (int nf=0; nf<2; nf++){
          int n = n0 + nrb + nf*16 + li;
          float bn = bias[n];
          u16x4 o;
          #pragma unroll
          for (int r=0; r<4; r++) o[r] = f2bf(acc[mf][nf][r] + bn);
          *(u16x4*)(Vt + (((size_t)(n>>6))<<16) + ((size_t)(n&63)<<10) + m) = o;
        }
      }
    }
    return;
  }
  // ---- gate blocks ----
  float* arr = (float*)smem;   // [4][1024] floats = 16 KB <= 17408
  #pragma unroll
  for (int u2=0; u2<4; u2++){
    int idx = u2*256 + t;
    float4 b4 = *(const float4*)(box + idx*4);
    arr[idx]        = (b4.x + b4.z)*0.5f;
    arr[1024+idx]   = (b4.y + b4.w)*0.5f;
    arr[2048+idx]   = log_hw(b4.z - b4.x + 1.0f);
    arr[3072+idx]   = log_hw(b4.w - b4.y + 1.0f);
  }
  const int i = blockIdx.x;
  float4 bi = *(const float4*)(box + i*4);
  float wi = bi.z - bi.x + 1.0f, hi = bi.w - bi.y + 1.0f;
  float Pi = (g==0) ? (bi.x+bi.z)*0.5f : (g==1) ? (bi.y+bi.w)*0.5f
           : (g==2) ? log_hw(wi) : log_hw(hi);
  float Ri = (g==0) ? 1.0f/wi : (g==1) ? 1.0f/hi : 1.0f;
  const bool doLog = (g < 2);
  bf16x8 wfs = {}, wfc = {};
  float wgb_li = 0.0f;
  if (li < 8){
    #pragma unroll
    for (int e=0; e<8; e++){
      wfs[e] = (__bf16)WGw[li*64 + g*8 + e];
      wfc[e] = (__bf16)WGw[li*64 + 32 + g*8 + e];
    }
    wgb_li = WGb[li];
  }
  __syncthreads();
  const float* parr = arr + g*1024;
  const float DMrev[8] = {15.9154943f, 6.7115094f, 2.8302196f, 1.1934938f,
                          0.5032921f, 0.2122365f, 0.08949941f, 0.0377416f};
  const int jbeg = w*256;
  for (int it=0; it<16; ++it){
    int j = jbeg + it*16 + li;
    float diff = (Pi - parr[j])*Ri;
    float lg = log_hw(fmaxf(fabsf(diff), 1e-3f));
    float dv = doLog ? lg : diff;
    bf16x8 afs, afc;
    #pragma unroll
    for (int e=0; e<8; e++){
      float rev = dv * DMrev[e];
      afs[e] = (__bf16)sin_rev(rev);
      afc[e] = (__bf16)cos_rev(rev);
    }
    f32x4 acc = (f32x4){0.f,0.f,0.f,0.f};
    acc = __builtin_amdgcn_mfma_f32_16x16x32_bf16(afs, wfs, acc, 0,0,0);
    acc = __builtin_amdgcn_mfma_f32_16x16x32_bf16(afc, wfc, acc, 0,0,0);
    if (li < 8){
      f16x4 o;
      #pragma unroll
      for (int r=0; r<4; r++)
        o[r] = (_Float16)fmaxf(acc[r] + wgb_li, 6.103515625e-05f);
      *(f16x4*)(wg16 + (((size_t)li<<20) + ((size_t)i<<10) + jbeg + it*16 + g*4)) = o;
    }
  }
}

// ================= k_attn3: JQ=256, NSPLIT=4, grid (8,8,4) — R6-proven =================
__global__ __launch_bounds__(512) void k_attn3(const ushort_t* __restrict__ Qb,
     const ushort_t* __restrict__ Kb, const ushort_t* __restrict__ Vt,
     const _Float16* __restrict__ wg, ushort_t* __restrict__ Xpt, float* __restrict__ rsp){
  __shared__ ushort_t Ks[256*68];
  __shared__ ushort_t Vs[64*264];
  const int t = threadIdx.x;
  const int itg = blockIdx.x, h = blockIdx.y, sp = blockIdx.z;
  const int jbeg = sp*JQ;
  {
    const int r = t >> 3, c = (t & 7)*8;
    #pragma unroll
    for (int p=0; p<4; p++){
      u16x8 kv = *(const u16x8*)(Kb + (size_t)(jbeg + p*64 + r)*DMODEL + h*DKH + c);
      *(u16x8*)(Ks + (p*64 + r)*68 + c) = kv;
      u16x8 vv = *(const u16x8*)(Vt + ((size_t)h<<16) + (size_t)r*NTOK + jbeg + p*64 + c);
      *(u16x8*)(Vs + r*264 + p*64 + c) = vv;
    }
  }
  const int lane = t & 63, w = t >> 6;
  const int i0 = (itg*8 + w)*16;
  const int li = lane & 15, g = lane >> 4;
  const ushort_t* qp = Qb + (size_t)(i0+li)*DMODEL + h*DKH + g*8;
  bf16x8 qf0 = *(const bf16x8*)(qp);
  bf16x8 qf1 = *(const bf16x8*)(qp + 32);
  const _Float16* gbase = wg + ((size_t)h<<20) + ((size_t)(i0+li)<<10) + jbeg + g*4;
  f32x4 xacc[4];
  #pragma unroll
  for (int mf=0; mf<4; mf++) xacc[mf] = (f32x4){0.f,0.f,0.f,0.f};
  float rsum = 0.f;
  __syncthreads();
  #pragma unroll
  for (int jj = 0; jj < JQ; jj += 32){
    const ushort_t* kp = Ks + (jj + li)*68 + g*8;
    bf16x8 a00 = *(const bf16x8*)(kp);
    bf16x8 a01 = *(const bf16x8*)(kp + 32);
    bf16x8 a10 = *(const bf16x8*)(kp + 16*68);
    bf16x8 a11 = *(const bf16x8*)(kp + 16*68 + 32);
    f32x4 s0 = (f32x4){0.f,0.f,0.f,0.f};
    f32x4 s1 = (f32x4){0.f,0.f,0.f,0.f};
    s0 = __builtin_amdgcn_mfma_f32_16x16x32_bf16(a00, qf0, s0, 0,0,0);
    s0 = __builtin_amdgcn_mfma_f32_16x16x32_bf16(a01, qf1, s0, 0,0,0);
    s1 = __builtin_amdgcn_mfma_f32_16x16x32_bf16(a10, qf0, s1, 0,0,0);
    s1 = __builtin_amdgcn_mfma_f32_16x16x32_bf16(a11, qf1, s1, 0,0,0);
    f16x4 g0 = *(const f16x4*)(gbase + jj);
    f16x4 g1 = *(const f16x4*)(gbase + jj + 16);
    float p[8];
    #pragma unroll
    for (int r=0; r<4; r++){ p[r]   = (float)g0[r] * exp_hw(s0[r]*0.125f); rsum += p[r]; }
    #pragma unroll
    for (int r=0; r<4; r++){ p[4+r] = (float)g1[r] * exp_hw(s1[r]*0.125f); rsum += p[4+r]; }
    bf16x8 pb;
    pb[0]=(__bf16)p[0]; pb[1]=(__bf16)p[1]; pb[2]=(__bf16)p[2]; pb[3]=(__bf16)p[3];
    pb[4]=(__bf16)p[4]; pb[5]=(__bf16)p[5]; pb[6]=(__bf16)p[6]; pb[7]=(__bf16)p[7];
    #pragma unroll
    for (int mf=0; mf<4; mf++){
      const ushort_t* vp = Vs + (size_t)(li + mf*16)*264 + jj + g*4;
      bf16x4 lo = *(const bf16x4*)(vp);
      bf16x4 hi = *(const bf16x4*)(vp + 16);
      bf16x8 vf = __builtin_shufflevector(lo, hi, 0,1,2,3,4,5,6,7);
      xacc[mf] = __builtin_amdgcn_mfma_f32_16x16x32_bf16(vf, pb, xacc[mf], 0,0,0);
    }
  }
  rsum += __shfl_xor(rsum, 16, 64);
  rsum += __shfl_xor(rsum, 32, 64);
  if (lane < 16) rsp[((size_t)sp*NHEAD + h)*NTOK + i0 + li] = rsum;
  __syncthreads();
  float* xw = (float*)Ks + w*(16*68);
  #pragma unroll
  for (int mf=0; mf<4; mf++)
    *(f32x4*)&xw[li*68 + mf*16 + g*4] = xacc[mf];
  __builtin_amdgcn_s_waitcnt(0);
  float xv[16];
  #pragma unroll
  for (int r=0; r<16; r++) xv[r] = xw[r*68 + lane];
  u16x8 o0, o1;
  #pragma unroll
  for (int r=0; r<8; r++){ o0[r] = f2bf(xv[r]); o1[r] = f2bf(xv[8+r]); }
  ushort_t* xp = Xpt + (((size_t)sp*NHEAD + h)*DKH + lane)*NTOK + i0;
  *(u16x8*)(xp)     = o0;
  *(u16x8*)(xp + 8) = o1;
}

// ================= k_back2: combine + LN0 + O-proj + final LN; 128 blocks x 8 rows =================
__global__ __launch_bounds__(512) void k_back2(
    const ushort_t* __restrict__ Xpt, const float* __restrict__ rsp,
    const float* __restrict__ inq,
    const float* __restrict__ ln0g, const float* __restrict__ ln0b,
    const ushort_t* __restrict__ Wob, const float* __restrict__ bo,
    const float* __restrict__ lng, const float* __restrict__ lnb,
    float* __restrict__ out){
  __shared__ ushort_t Ab[8][520];
  __shared__ float    Y[8][516];
  __shared__ float    red[8][8][2];
  const int t = threadIdx.x, lane = t & 63, w = t >> 6;
  const int li = lane & 15, g = lane >> 4;
  const int m0 = blockIdx.x*8;
  // ---- combine + LN0: wave w owns row m0+w ----
  {
    const int n = m0 + w;
    const int h = n >> 7, dk = (n >> 1) & 63, mo = (n & 1)*512;
    float x[8];
    float sum = 0.f, sq = 0.f;
    #pragma unroll
    for (int c=0; c<8; c++){
      int d = c*64 + lane;
      int i = mo + d;
      float sv = 0.f, rv = 0.f;
      #pragma unroll
      for (int sp=0; sp<NSPLIT; sp++){
        sv += bf2f(Xpt[(((size_t)sp*NHEAD + h)*DKH + dk)*NTOK + i]);
        rv += rsp[((size_t)sp*NHEAD + h)*NTOK + i];
      }
      x[c] = sv/rv + inq[(size_t)n*DMODEL + d];
      sum += x[c]; sq += x[c]*x[c];
    }
    sum = wave_sum_f(sum);
    sq  = wave_sum_f(sq);
    float mean = sum * (1.0f/512.0f);
    float var = sq * (1.0f/512.0f) - mean*mean;
    float rs = rsqrtf(var + 1e-5f);
    #pragma unroll
    for (int c=0; c<8; c++){
      int d = c*64 + lane;
      float y = (x[c]-mean)*rs*ln0g[d] + ln0b[d];
      Y[w][d] = y;
      Ab[w][d] = f2bf(y);
    }
  }
  __syncthreads();
  // ---- O-projection (rows m0..m0+7) + final LN ----
  const int n0 = w*64;
  const ushort_t* ar = &Ab[li & 7][g*8];
  const ushort_t* wr = Wob + (size_t)(n0+li)*DMODEL + g*8;
  f32x4 acc[4] = {};
  #pragma unroll
  for (int k0=0; k0<DMODEL; k0+=64){
    bf16x8 afa = *(const bf16x8*)(ar + k0);
    bf16x8 afb = *(const bf16x8*)(ar + k0 + 32);
    #pragma unroll
    for (int nf=0; nf<4; nf++){
      const ushort_t* wp = wr + (size_t)nf*16*DMODEL + k0;
      bf16x8 wfa = *(const bf16x8*)(wp);
      bf16x8 wfb = *(const bf16x8*)(wp + 32);
      acc[nf] = __builtin_amdgcn_mfma_f32_16x16x32_bf16(wfa, afa, acc[nf], 0,0,0);
      acc[nf] = __builtin_amdgcn_mfma_f32_16x16x32_bf16(wfb, afb, acc[nf], 0,0,0);
    }
  }
  float s = 0.f, qq = 0.f;
  f32x4 v[4];
  #pragma unroll
  for (int nf=0; nf<4; nf++){
    int n = n0 + nf*16 + g*4;
    f32x4 b4 = *(const f32x4*)(bo + n);
    #pragma unroll
    for (int r=0; r<4; r++){
      float x = acc[nf][r] + b4[r] + Y[li & 7][n + r];
      v[nf][r] = x; s += x; qq += x*x;
    }
  }
  s  += __shfl_xor(s, 16, 64);  s  += __shfl_xor(s, 32, 64);
  qq += __shfl_xor(qq, 16, 64); qq += __shfl_xor(qq, 32, 64);
  if (g == 0 && li < 8){ red[w][li][0] = s; red[w][li][1] = qq; }
  __syncthreads();
  float S = 0.f, Q = 0.f;
  #pragma unroll
  for (int u=0; u<8; u++){ S += red[u][li & 7][0]; Q += red[u][li & 7][1]; }
  float mean = S * (1.0f/512.0f);
  float var = Q * (1.0f/512.0f) - mean*mean;
  float rs = rsqrtf(var + 1e-5f);
  if (li < 8){
    const int m = m0 + li;
    #pragma unroll
    for (int nf=0; nf<4; nf++){
      int n = n0 + nf*16 + g*4;
      f32x4 g4 = *(const f32x4*)(lng + n);
      f32x4 be = *(const f32x4*)(lnb + n);
      f32x4 o;
      #pragma unroll
      for (int r=0; r<4; r++) o[r] = (v[nf][r]-mean)*rs*g4[r] + be[r];
      *(f32x4*)(out + (size_t)m*DMODEL + n) = o;
    }
  }
}

extern "C" void kernel_launch(void* const* d_in, const int* in_sizes, int n_in,
                              void* d_out, int out_size, void* d_ws, size_t ws_size,
                              hipStream_t stream){
  (void)in_sizes; (void)n_in; (void)out_size; (void)ws_size;
  const float* in_q = (const float*)d_in[0];
  const float* in_k = (const float*)d_in[1];
  const float* in_v = (const float*)d_in[2];
  const float* box  = (const float*)d_in[3];
  const float* Wq   = (const float*)d_in[4];
  const float* bq   = (const float*)d_in[5];
  const float* Wk   = (const float*)d_in[6];
  const float* bk   = (const float*)d_in[7];
  const float* Wv   = (const float*)d_in[8];
  const float* bv   = (const float*)d_in[9];
  const float* Wo   = (const float*)d_in[10];
  const float* bo   = (const float*)d_in[11];
  const float* WGw  = (const float*)d_in[12];
  const float* WGb  = (const float*)d_in[13];
  const float* ln0g = (const float*)d_in[14];
  const float* ln0b = (const float*)d_in[15];
  const float* lng  = (const float*)d_in[16];
  const float* lnb  = (const float*)d_in[17];

  float* ws = (float*)d_ws;
  ushort_t* Wob  = (ushort_t*)(ws + 0);             // [512][512] bf16
  ushort_t* Qb   = (ushort_t*)(ws + 131072);        // [1024][512] bf16
  ushort_t* Kb   = (ushort_t*)(ws + 393216);
  ushort_t* Vt   = (ushort_t*)(ws + 655360);        // [8][64][1024] bf16
  _Float16* wg16 = (_Float16*)(ws + 917504);        // [8][1024][1024] fp16 (16 MB)
  ushort_t* Xpt  = (ushort_t*)(ws + 5111808);       // [4][8][64][1024] bf16 (4 MB)
  float*    rsp  = ws + 6160384;                    // [4][8][1024]
  float*    out  = (float*)d_out;

  k_front2<<<dim3(1536), dim3(256), 0, stream>>>(box, WGw, WGb, wg16,
            in_q, in_k, in_v, Wq, Wk, Wv, Wo, bq, bk, bv, Qb, Kb, Vt, Wob);
  k_attn3<<<dim3(8,8,4), dim3(512), 0, stream>>>(Qb, Kb, Vt, wg16, Xpt, rsp);
  k_back2<<<dim3(128), dim3(512), 0, stream>>>(Xpt, rsp, in_q, ln0g, ln0b,
            Wob, bo, lng, lnb, out);
}